// Round 5
// baseline (350.383 us; speedup 1.0000x reference)
//
#include <hip/hip_runtime.h>
#include <math.h>

typedef __attribute__((ext_vector_type(8))) short short8;
typedef __attribute__((ext_vector_type(4))) float f32x4;
typedef __attribute__((ext_vector_type(16))) float f32x16;
typedef __attribute__((ext_vector_type(4))) int int32x4;
typedef unsigned short bf16_t;

#define GLOAD_LDS16(g, l)                                                   \
    __builtin_amdgcn_global_load_lds(                                       \
        (__attribute__((address_space(1))) void*)(g),                       \
        (__attribute__((address_space(3))) void*)(l), 16, 0, 0)

__device__ __forceinline__ bf16_t f2b_rne(float f) {
    unsigned int u = __float_as_uint(f);
    u += 0x7FFFu + ((u >> 16) & 1u);
    return (bf16_t)(u >> 16);
}

__device__ __forceinline__ void store_out(bf16_t* p, float v) { *p = f2b_rne(v); }
__device__ __forceinline__ void store_out(float* p, float v) { *p = v; }

// ---------------------------------------------------------------------------
// fp32 -> bf16 conversion
// ---------------------------------------------------------------------------
__global__ __launch_bounds__(256) void f2b_kernel(const float* __restrict__ in,
                                                  bf16_t* __restrict__ out, int n4) {
    int stride = gridDim.x * 256;
    for (int i = blockIdx.x * 256 + threadIdx.x; i < n4; i += stride) {
        float4 v = ((const float4*)in)[i];
        ushort4 p;
        p.x = f2b_rne(v.x); p.y = f2b_rne(v.y);
        p.z = f2b_rne(v.z); p.w = f2b_rne(v.w);
        ((ushort4*)out)[i] = p;
    }
}

// ---------------------------------------------------------------------------
// Relative-position bias table: tab[h][(k-q)+1023]  (validated round 2)
// ---------------------------------------------------------------------------
__global__ void build_bias_tab(const float* __restrict__ emb, float* __restrict__ tab) {
    int idx = blockIdx.x * 256 + threadIdx.x;
    if (idx >= 2047) return;
    int rel = idx - 1023;
    int rb = rel > 0 ? 16 : 0;
    int rp = rel < 0 ? -rel : rel;
    int bucket;
    if (rp < 8) {
        bucket = rb + rp;
    } else {
        float t = logf((float)rp * 0.125f);
        int vi = 8 + (int)(t / 2.772588722239781f * 8.0f);
        bucket = rb + (vi < 15 ? vi : 15);
    }
    #pragma unroll
    for (int hh = 0; hh < 16; hh++)
        tab[hh * 2048 + idx] = emb[bucket * 16 + hh];
}

// ---------------------------------------------------------------------------
// bf16 MFMA GEMM (m97 structure) + XCD-aware swizzle (1D grid, nwg % 8 == 0).
// C[M,N] = A[M,1024] * B[N,1024]^T
// ---------------------------------------------------------------------------
template <typename OT>
__global__ __launch_bounds__(256) void gemm_mfma(const bf16_t* __restrict__ A,
                                                 const bf16_t* __restrict__ B,
                                                 OT* __restrict__ C, int N, int gx) {
    __shared__ __align__(16) bf16_t As[128 * 32];
    __shared__ __align__(16) bf16_t Bs[128 * 32];
    const int nwg = gridDim.x;
    const int cpx = nwg >> 3;
    const int swz = (blockIdx.x & 7) * cpx + (blockIdx.x >> 3);
    const int bx = swz % gx, by = swz / gx;

    const int tid = threadIdx.x;
    const int lane = tid & 63;
    const int wv = tid >> 6;
    const int wr = wv >> 1, wc = wv & 1;
    const int m0 = by * 128, n0 = bx * 128;
    const int cc = lane & 15, cg = lane >> 4;

    f32x4 acc[4][4];
    #pragma unroll
    for (int i = 0; i < 4; i++)
        #pragma unroll
        for (int j = 0; j < 4; j++) acc[i][j] = {0.f, 0.f, 0.f, 0.f};

    for (int k0 = 0; k0 < 1024; k0 += 32) {
        __syncthreads();
        #pragma unroll
        for (int it = 0; it < 2; it++) {
            int c = it * 256 + tid;
            int r = c >> 2, kc = (c & 3) * 8;
            GLOAD_LDS16(A + (size_t)(m0 + r) * 1024 + k0 + kc, &As[c * 8]);
            GLOAD_LDS16(B + (size_t)(n0 + r) * 1024 + k0 + kc, &Bs[c * 8]);
        }
        __syncthreads();

        short8 af[4], bf[4];
        #pragma unroll
        for (int mf = 0; mf < 4; mf++)
            af[mf] = *(const short8*)&As[(wr * 64 + mf * 16 + cc) * 32 + cg * 8];
        #pragma unroll
        for (int nf = 0; nf < 4; nf++)
            bf[nf] = *(const short8*)&Bs[(wc * 64 + nf * 16 + cc) * 32 + cg * 8];
        #pragma unroll
        for (int mf = 0; mf < 4; mf++)
            #pragma unroll
            for (int nf = 0; nf < 4; nf++)
                acc[mf][nf] = __builtin_amdgcn_mfma_f32_16x16x32_bf16(
                    af[mf], bf[nf], acc[mf][nf], 0, 0, 0);
    }

    #pragma unroll
    for (int mf = 0; mf < 4; mf++)
        #pragma unroll
        for (int j = 0; j < 4; j++) {
            size_t row = (size_t)(m0 + wr * 64 + mf * 16 + cg * 4 + j);
            OT* cp = C + row * N + n0 + wc * 64 + cc;
            #pragma unroll
            for (int nf = 0; nf < 4; nf++) store_out(cp + nf * 16, acc[mf][nf][j]);
        }
}

// ---------------------------------------------------------------------------
// V transpose: qkv V-part [B,S,3072] -> vt [B,H,64,1024]
// ---------------------------------------------------------------------------
__global__ __launch_bounds__(256) void transpose_v(const bf16_t* __restrict__ qkv,
                                                   bf16_t* __restrict__ vt) {
    const int tid = threadIdx.x;
    const int d = tid & 63, so = tid >> 6;
    const int s0 = blockIdx.x * 32 + so * 8;
    const int h = blockIdx.y, b = blockIdx.z;
    const bf16_t* src = qkv + (size_t)(b * 1024 + s0) * 3072 + 2048 + h * 64 + d;
    short8 v;
    #pragma unroll
    for (int j = 0; j < 8; j++) v[j] = (short)src[(size_t)j * 3072];
    *(short8*)(vt + ((size_t)(b * 16 + h) * 64 + d) * 1024 + s0) = v;
}

// ---------------------------------------------------------------------------
// Swapped-operand MFMA flash attention, round 4:
//  + XCD swizzle: all 8 q-chunks of one (b,h) land on ONE XCD (L2-resident K/V)
//  + K-fragment register double-buffer (1 tile ahead); V issued early in body
//  + s_setprio(1) around MFMA clusters
// Grid: 1024 blocks x 256 thr (4 waves); wave owns 32 q rows; 32 k-tiles of 32.
// ---------------------------------------------------------------------------
__global__ __launch_bounds__(256, 3) void attn_mfma3(const bf16_t* __restrict__ qkv,
                                                     const float* __restrict__ tab,
                                                     const bf16_t* __restrict__ vt,
                                                     bf16_t* __restrict__ attn_out) {
    __shared__ float bias2[2304];
    __shared__ bf16_t Ol[4 * 32 * 68];

    // swizzle decode: i%8 selects XCD; 8 consecutive i>>3 slots = 8 q-chunks of g
    const int i = blockIdx.x;
    const int g = ((i >> 6) << 3) + (i & 7);   // b*16 + h
    const int qc = (i >> 3) & 7;
    const int b = g >> 4, h = g & 15;
    const int q0 = qc * 128;

    const int tid = threadIdx.x;
    const int lane = tid & 63;
    const int w = tid >> 6;
    const int l31 = lane & 31;
    const int hi = lane >> 5;

    const float* tabh = tab + h * 2048;
    const int wbase = 896 - q0;
    #pragma unroll
    for (int it = 0; it < 5; it++) {
        int j = it * 256 + tid;
        if (j < 1151) {
            bias2[2 * j]     = tabh[wbase + j];
            bias2[2 * j + 1] = tabh[wbase + j + 1];
        }
    }

    const size_t rs = 3072;
    const bf16_t* Qg = qkv + (size_t)b * 1024 * rs + h * 64;
    const bf16_t* Kg = Qg + 1024;
    const bf16_t* vth = vt + (size_t)(b * 16 + h) * 64 * 1024;

    const int qloc = w * 32 + l31;
    short8 qf[4];
    #pragma unroll
    for (int s = 0; s < 4; s++)
        qf[s] = *(const short8*)(Qg + (size_t)(q0 + qloc) * rs + 8 * hi + 16 * s);

    f32x16 O0 = (f32x16)0.f, O1 = (f32x16)0.f;
    float m_run = -1e30f, l_run = 0.f;

    const bf16_t* krow = Kg + (size_t)l31 * rs + 8 * hi;
    const bf16_t* vrow0 = vth + (size_t)l31 * 1024 + 8 * hi;
    const bf16_t* vrow1 = vth + (size_t)(32 + l31) * 1024 + 8 * hi;

    auto loadk = [&](short8 (&dst)[4], int kt) {
        const bf16_t* kr = krow + (size_t)kt * 32 * rs;
        #pragma unroll
        for (int s = 0; s < 4; s++) dst[s] = *(const short8*)(kr + 16 * s);
    };

    auto compute = [&](short8 (&kf)[4], int kt) {
        const int k0 = kt * 32;
        // QK^T (swapped): S^T[kk][q]
        f32x16 S = (f32x16)0.f;
        __builtin_amdgcn_s_setprio(1);
        #pragma unroll
        for (int s = 0; s < 4; s++)
            S = __builtin_amdgcn_mfma_f32_32x32x16_bf16(kf[s], qf[s], S, 0, 0, 0);
        __builtin_amdgcn_s_setprio(0);

        // issue V loads now; consumed after softmax (~250 cyc slack)
        const bf16_t* v0p = vrow0 + k0;
        const bf16_t* v1p = vrow1 + k0;
        short8 vf0 = *(const short8*)v0p;
        short8 vf1 = *(const short8*)(v0p + 16);
        short8 vf2 = *(const short8*)v1p;
        short8 vf3 = *(const short8*)(v1p + 16);

        // bias add: reg r -> kk = (r&3) + 8*(r>>2) + 4*hi
        float p[16];
        #pragma unroll
        for (int gg = 0; gg < 4; gg++) {
            int bi = k0 + 8 * gg + 4 * hi + 127 - qloc;
            float2 b0 = *(const float2*)&bias2[2 * bi];
            float2 b1 = *(const float2*)&bias2[2 * (bi + 2)];
            p[4 * gg + 0] = S[4 * gg + 0] + b0.x;
            p[4 * gg + 1] = S[4 * gg + 1] + b0.y;
            p[4 * gg + 2] = S[4 * gg + 2] + b1.x;
            p[4 * gg + 3] = S[4 * gg + 3] + b1.y;
        }

        // online softmax, lane-local stats, defer-max THR=8
        float pmax = p[0];
        #pragma unroll
        for (int r = 1; r < 16; r++) pmax = fmaxf(pmax, p[r]);
        pmax = fmaxf(pmax, __shfl_xor(pmax, 32));
        if (!__all(pmax - m_run <= 8.f)) {
            float mn = fmaxf(m_run, pmax);
            float sc = __expf(m_run - mn);
            l_run *= sc;
            #pragma unroll
            for (int r = 0; r < 16; r++) { O0[r] *= sc; O1[r] *= sc; }
            m_run = mn;
        }
        float rsum = 0.f;
        #pragma unroll
        for (int r = 0; r < 16; r++) { p[r] = __expf(p[r] - m_run); rsum += p[r]; }
        rsum += __shfl_xor(rsum, 32);
        l_run += rsum;

        // pack P to bf16; exchange partner halves to build PV B-frags
        unsigned int wv[8];
        #pragma unroll
        for (int ii = 0; ii < 8; ii++) {
            unsigned int t;
            asm("v_cvt_pk_bf16_f32 %0, %1, %2" : "=v"(t) : "v"(p[2 * ii]), "v"(p[2 * ii + 1]));
            wv[ii] = t;
        }
        unsigned int x0 = __shfl_xor(hi ? wv[0] : wv[2], 32);
        unsigned int x1 = __shfl_xor(hi ? wv[1] : wv[3], 32);
        unsigned int x2 = __shfl_xor(hi ? wv[4] : wv[6], 32);
        unsigned int x3 = __shfl_xor(hi ? wv[5] : wv[7], 32);
        int32x4 pf0i, pf1i;
        if (hi) {
            pf0i = (int32x4){(int)x0, (int)x1, (int)wv[2], (int)wv[3]};
            pf1i = (int32x4){(int)x2, (int)x3, (int)wv[6], (int)wv[7]};
        } else {
            pf0i = (int32x4){(int)wv[0], (int)wv[1], (int)x0, (int)x1};
            pf1i = (int32x4){(int)wv[4], (int)wv[5], (int)x2, (int)x3};
        }
        short8 pf0 = __builtin_bit_cast(short8, pf0i);
        short8 pf1 = __builtin_bit_cast(short8, pf1i);

        // PV (swapped): O^T[d][q] += Vt-frag x P-frag
        __builtin_amdgcn_s_setprio(1);
        O0 = __builtin_amdgcn_mfma_f32_32x32x16_bf16(vf0, pf0, O0, 0, 0, 0);
        O0 = __builtin_amdgcn_mfma_f32_32x32x16_bf16(vf1, pf1, O0, 0, 0, 0);
        O1 = __builtin_amdgcn_mfma_f32_32x32x16_bf16(vf2, pf0, O1, 0, 0, 0);
        O1 = __builtin_amdgcn_mfma_f32_32x32x16_bf16(vf3, pf1, O1, 0, 0, 0);
        __builtin_amdgcn_s_setprio(0);
    };

    __syncthreads();  // bias2 ready

    short8 kA[4], kB[4];
    loadk(kA, 0);
    for (int kt = 0; kt < 32; kt += 2) {
        loadk(kB, kt + 1);
        compute(kA, kt);
        if (kt < 30) loadk(kA, kt + 2);
        compute(kB, kt + 1);
    }

    // epilogue: normalize, LDS-bounce O^T -> row-major, coalesced stores
    float inv = 1.f / l_run;
    bf16_t* olw = &Ol[w * 32 * 68];
    #pragma unroll
    for (int r = 0; r < 16; r++) {
        int dr = (r & 3) + 8 * (r >> 2) + 4 * hi;
        olw[l31 * 68 + dr]      = f2b_rne(O0[r] * inv);
        olw[l31 * 68 + dr + 32] = f2b_rne(O1[r] * inv);
    }
    bf16_t* outp = attn_out + (size_t)(b * 1024 + q0 + w * 32) * 1024 + h * 64;
    #pragma unroll 4
    for (int i2 = 0; i2 < 32; i2++)
        outp[(size_t)i2 * 1024 + lane] = olw[i2 * 68 + lane];
}

// ---------------------------------------------------------------------------
extern "C" void kernel_launch(void* const* d_in, const int* in_sizes, int n_in,
                              void* d_out, int out_size, void* d_ws, size_t ws_size,
                              hipStream_t stream) {
    const float* hs   = (const float*)d_in[0];  // [8,1024,1024]
    const float* wqkv = (const float*)d_in[1];  // [3072,1024]
    const float* emb  = (const float*)d_in[2];  // [32,16]
    const float* wout = (const float*)d_in[3];  // [1024,1024]
    float* out = (float*)d_out;                 // [8,1024,1024] fp32

    char* p = (char*)d_ws;
    bf16_t* qkvb  = (bf16_t*)p; p += (size_t)8192 * 3072 * 2;  // 48 MB
    bf16_t* attnb = (bf16_t*)p; p += (size_t)8192 * 1024 * 2;  // 16 MB
    bf16_t* hsb   = (bf16_t*)p; p += (size_t)8192 * 1024 * 2;  // 16 MB
    bf16_t* wqkvb = (bf16_t*)p; p += (size_t)3072 * 1024 * 2;  //  6 MB
    bf16_t* woutb = (bf16_t*)p; p += (size_t)1024 * 1024 * 2;  //  2 MB
    bf16_t* vtb   = (bf16_t*)p; p += (size_t)8 * 16 * 64 * 1024 * 2;  // 16 MB
    float*  tab   = (float*)p;                                 // 128 KB

    f2b_kernel<<<2048, 256, 0, stream>>>(hs, hsb, 8192 * 1024 / 4);
    f2b_kernel<<<768, 256, 0, stream>>>(wqkv, wqkvb, 3072 * 1024 / 4);
    f2b_kernel<<<256, 256, 0, stream>>>(wout, woutb, 1024 * 1024 / 4);
    build_bias_tab<<<8, 256, 0, stream>>>(emb, tab);

    gemm_mfma<bf16_t><<<1536, 256, 0, stream>>>(hsb, wqkvb, qkvb, 3072, 24);
    transpose_v<<<dim3(32, 16, 8), 256, 0, stream>>>(qkvb, vtb);
    attn_mfma3<<<1024, 256, 0, stream>>>(qkvb, tab, vtb, attnb);
    gemm_mfma<float><<<512, 256, 0, stream>>>(attnb, woutb, out, 1024, 8);
}

// Round 6
// 258.485 us; speedup vs baseline: 1.3555x; 1.3555x over previous
//
#include <hip/hip_runtime.h>
#include <math.h>

typedef __attribute__((ext_vector_type(8))) short short8;
typedef __attribute__((ext_vector_type(4))) float f32x4;
typedef __attribute__((ext_vector_type(16))) float f32x16;
typedef __attribute__((ext_vector_type(4))) int int32x4;
typedef unsigned short bf16_t;

#define GLOAD_LDS16(g, l)                                                   \
    __builtin_amdgcn_global_load_lds(                                       \
        (__attribute__((address_space(1))) void*)(g),                       \
        (__attribute__((address_space(3))) void*)(l), 16, 0, 0)

__device__ __forceinline__ bf16_t f2b_rne(float f) {
    unsigned int u = __float_as_uint(f);
    u += 0x7FFFu + ((u >> 16) & 1u);
    return (bf16_t)(u >> 16);
}

__device__ __forceinline__ void store_out(bf16_t* p, float v) { *p = f2b_rne(v); }
__device__ __forceinline__ void store_out(float* p, float v) { *p = v; }

// ---------------------------------------------------------------------------
// fp32 -> bf16 conversion
// ---------------------------------------------------------------------------
__global__ __launch_bounds__(256) void f2b_kernel(const float* __restrict__ in,
                                                  bf16_t* __restrict__ out, int n4) {
    int stride = gridDim.x * 256;
    for (int i = blockIdx.x * 256 + threadIdx.x; i < n4; i += stride) {
        float4 v = ((const float4*)in)[i];
        ushort4 p;
        p.x = f2b_rne(v.x); p.y = f2b_rne(v.y);
        p.z = f2b_rne(v.z); p.w = f2b_rne(v.w);
        ((ushort4*)out)[i] = p;
    }
}

// ---------------------------------------------------------------------------
// Relative-position bias table: tab[h][(k-q)+1023]  (validated round 2)
// ---------------------------------------------------------------------------
__global__ void build_bias_tab(const float* __restrict__ emb, float* __restrict__ tab) {
    int idx = blockIdx.x * 256 + threadIdx.x;
    if (idx >= 2047) return;
    int rel = idx - 1023;
    int rb = rel > 0 ? 16 : 0;
    int rp = rel < 0 ? -rel : rel;
    int bucket;
    if (rp < 8) {
        bucket = rb + rp;
    } else {
        float t = logf((float)rp * 0.125f);
        int vi = 8 + (int)(t / 2.772588722239781f * 8.0f);
        bucket = rb + (vi < 15 ? vi : 15);
    }
    #pragma unroll
    for (int hh = 0; hh < 16; hh++)
        tab[hh * 2048 + idx] = emb[bucket * 16 + hh];
}

// ---------------------------------------------------------------------------
// bf16 MFMA GEMM (m97 structure) + XCD-aware swizzle (1D grid, nwg % 8 == 0).
// C[M,N] = A[M,1024] * B[N,1024]^T
// ---------------------------------------------------------------------------
template <typename OT>
__global__ __launch_bounds__(256) void gemm_mfma(const bf16_t* __restrict__ A,
                                                 const bf16_t* __restrict__ B,
                                                 OT* __restrict__ C, int N, int gx) {
    __shared__ __align__(16) bf16_t As[128 * 32];
    __shared__ __align__(16) bf16_t Bs[128 * 32];
    const int nwg = gridDim.x;
    const int cpx = nwg >> 3;
    const int swz = (blockIdx.x & 7) * cpx + (blockIdx.x >> 3);
    const int bx = swz % gx, by = swz / gx;

    const int tid = threadIdx.x;
    const int lane = tid & 63;
    const int wv = tid >> 6;
    const int wr = wv >> 1, wc = wv & 1;
    const int m0 = by * 128, n0 = bx * 128;
    const int cc = lane & 15, cg = lane >> 4;

    f32x4 acc[4][4];
    #pragma unroll
    for (int i = 0; i < 4; i++)
        #pragma unroll
        for (int j = 0; j < 4; j++) acc[i][j] = {0.f, 0.f, 0.f, 0.f};

    for (int k0 = 0; k0 < 1024; k0 += 32) {
        __syncthreads();
        #pragma unroll
        for (int it = 0; it < 2; it++) {
            int c = it * 256 + tid;
            int r = c >> 2, kc = (c & 3) * 8;
            GLOAD_LDS16(A + (size_t)(m0 + r) * 1024 + k0 + kc, &As[c * 8]);
            GLOAD_LDS16(B + (size_t)(n0 + r) * 1024 + k0 + kc, &Bs[c * 8]);
        }
        __syncthreads();

        short8 af[4], bf[4];
        #pragma unroll
        for (int mf = 0; mf < 4; mf++)
            af[mf] = *(const short8*)&As[(wr * 64 + mf * 16 + cc) * 32 + cg * 8];
        #pragma unroll
        for (int nf = 0; nf < 4; nf++)
            bf[nf] = *(const short8*)&Bs[(wc * 64 + nf * 16 + cc) * 32 + cg * 8];
        #pragma unroll
        for (int mf = 0; mf < 4; mf++)
            #pragma unroll
            for (int nf = 0; nf < 4; nf++)
                acc[mf][nf] = __builtin_amdgcn_mfma_f32_16x16x32_bf16(
                    af[mf], bf[nf], acc[mf][nf], 0, 0, 0);
    }

    #pragma unroll
    for (int mf = 0; mf < 4; mf++)
        #pragma unroll
        for (int j = 0; j < 4; j++) {
            size_t row = (size_t)(m0 + wr * 64 + mf * 16 + cg * 4 + j);
            OT* cp = C + row * N + n0 + wc * 64 + cc;
            #pragma unroll
            for (int nf = 0; nf < 4; nf++) store_out(cp + nf * 16, acc[mf][nf][j]);
        }
}

// ---------------------------------------------------------------------------
// K relayout into MFMA A-fragment order:
// klin[bh][kt][s][lane][j] = K[key = kt*32 + (lane&31)][d = 16s + 8(lane>>5) + j]
// 16B granule per thread; source 16B is contiguous in qkvb.
// ---------------------------------------------------------------------------
__global__ __launch_bounds__(256) void relayout_k(const bf16_t* __restrict__ qkvb,
                                                  bf16_t* __restrict__ klin) {
    int gid = blockIdx.x * 256 + threadIdx.x;   // 1M granules
    int lane = gid & 63;
    int s = (gid >> 6) & 3;
    int kt = (gid >> 8) & 31;
    int bh = gid >> 13;
    int b = bh >> 4, h = bh & 15;
    int key = kt * 32 + (lane & 31);
    int d0 = 16 * s + 8 * (lane >> 5);
    const bf16_t* src = qkvb + (size_t)(b * 1024 + key) * 3072 + 1024 + h * 64 + d0;
    *(short8*)(klin + (size_t)gid * 8) = *(const short8*)src;
}

// ---------------------------------------------------------------------------
// V relayout into PV A-fragment order (transposed):
// vt2[bh][kt][half*2+s2][lane][j] = V[key = kt*32+16*s2+8*(lane>>5)+j][d=(lane&31)+32*half]
// 8-key gather per thread (stride 6KB), L1-amortized within block; one-time 16MB.
// ---------------------------------------------------------------------------
__global__ __launch_bounds__(256) void relayout_v(const bf16_t* __restrict__ qkvb,
                                                  bf16_t* __restrict__ vt2) {
    int gid = blockIdx.x * 256 + threadIdx.x;   // 1M granules
    int lane = gid & 63;
    int i = (gid >> 6) & 3;                     // half*2 + s2
    int kt = (gid >> 8) & 31;
    int bh = gid >> 13;
    int b = bh >> 4, h = bh & 15;
    int half = i >> 1, s2 = i & 1;
    int key0 = kt * 32 + 16 * s2 + 8 * (lane >> 5);
    int d = (lane & 31) + 32 * half;
    const bf16_t* src = qkvb + (size_t)(b * 1024 + key0) * 3072 + 2048 + h * 64 + d;
    short8 v;
    #pragma unroll
    for (int j = 0; j < 8; j++) v[j] = (short)src[(size_t)j * 3072];
    *(short8*)(vt2 + (size_t)gid * 8) = v;
}

// ---------------------------------------------------------------------------
// Swapped-operand MFMA flash attention, round 6:
// All K/V fragment loads are fully-coalesced dwordx4 from pre-swizzled
// klin/vt2 (fragment-order layouts). No LDS staging, no barriers in k-loop,
// no setprio. K register-double-buffered; V issued early in compute body.
// Grid: 1024 blocks (XCD swizzle), 256 thr / 4 waves; wave owns 32 q.
// ---------------------------------------------------------------------------
__global__ __launch_bounds__(256, 3) void attn_mfma4(const bf16_t* __restrict__ qkv,
                                                     const float* __restrict__ tab,
                                                     const bf16_t* __restrict__ klin,
                                                     const bf16_t* __restrict__ vt2,
                                                     bf16_t* __restrict__ attn_out) {
    __shared__ float bias2[2304];
    __shared__ bf16_t Ol[4 * 32 * 68];

    // swizzle decode: i%8 selects XCD; 8 consecutive i>>3 slots = 8 q-chunks of g
    const int i = blockIdx.x;
    const int g = ((i >> 6) << 3) + (i & 7);   // b*16 + h
    const int qc = (i >> 3) & 7;
    const int b = g >> 4, h = g & 15;
    const int q0 = qc * 128;

    const int tid = threadIdx.x;
    const int lane = tid & 63;
    const int w = tid >> 6;
    const int l31 = lane & 31;
    const int hi = lane >> 5;

    const float* tabh = tab + h * 2048;
    const int wbase = 896 - q0;
    #pragma unroll
    for (int it = 0; it < 5; it++) {
        int j = it * 256 + tid;
        if (j < 1151) {
            bias2[2 * j]     = tabh[wbase + j];
            bias2[2 * j + 1] = tabh[wbase + j + 1];
        }
    }

    const size_t rs = 3072;
    const bf16_t* Qg = qkv + (size_t)b * 1024 * rs + h * 64;
    const bf16_t* kl = klin + (size_t)g * 65536;
    const bf16_t* vl = vt2 + (size_t)g * 65536;

    const int qloc = w * 32 + l31;
    short8 qf[4];
    #pragma unroll
    for (int s = 0; s < 4; s++)
        qf[s] = *(const short8*)(Qg + (size_t)(q0 + qloc) * rs + 8 * hi + 16 * s);

    f32x16 O0 = (f32x16)0.f, O1 = (f32x16)0.f;
    float m_run = -1e30f, l_run = 0.f;

    auto loadk = [&](short8 (&dst)[4], int kt) {
        const bf16_t* kp = kl + (size_t)kt * 2048 + lane * 8;
        #pragma unroll
        for (int s = 0; s < 4; s++) dst[s] = *(const short8*)(kp + s * 512);
    };

    auto compute = [&](short8 (&kf)[4], int kt) {
        const int k0 = kt * 32;
        // V fragment loads issued first; consumed after QK^T + softmax
        const bf16_t* vp = vl + (size_t)kt * 2048 + lane * 8;
        short8 vf0 = *(const short8*)vp;
        short8 vf1 = *(const short8*)(vp + 512);
        short8 vf2 = *(const short8*)(vp + 1024);
        short8 vf3 = *(const short8*)(vp + 1536);

        // QK^T (swapped): S^T[kk][q]
        f32x16 S = (f32x16)0.f;
        #pragma unroll
        for (int s = 0; s < 4; s++)
            S = __builtin_amdgcn_mfma_f32_32x32x16_bf16(kf[s], qf[s], S, 0, 0, 0);

        // bias add: reg r -> kk = (r&3) + 8*(r>>2) + 4*hi
        float p[16];
        #pragma unroll
        for (int gg = 0; gg < 4; gg++) {
            int bi = k0 + 8 * gg + 4 * hi + 127 - qloc;
            float2 b0 = *(const float2*)&bias2[2 * bi];
            float2 b1 = *(const float2*)&bias2[2 * (bi + 2)];
            p[4 * gg + 0] = S[4 * gg + 0] + b0.x;
            p[4 * gg + 1] = S[4 * gg + 1] + b0.y;
            p[4 * gg + 2] = S[4 * gg + 2] + b1.x;
            p[4 * gg + 3] = S[4 * gg + 3] + b1.y;
        }

        // online softmax, lane-local stats, defer-max THR=8
        float pmax = p[0];
        #pragma unroll
        for (int r = 1; r < 16; r++) pmax = fmaxf(pmax, p[r]);
        pmax = fmaxf(pmax, __shfl_xor(pmax, 32));
        if (!__all(pmax - m_run <= 8.f)) {
            float mn = fmaxf(m_run, pmax);
            float sc = __expf(m_run - mn);
            l_run *= sc;
            #pragma unroll
            for (int r = 0; r < 16; r++) { O0[r] *= sc; O1[r] *= sc; }
            m_run = mn;
        }
        float rsum = 0.f;
        #pragma unroll
        for (int r = 0; r < 16; r++) { p[r] = __expf(p[r] - m_run); rsum += p[r]; }
        rsum += __shfl_xor(rsum, 32);
        l_run += rsum;

        // pack P to bf16; exchange partner halves to build PV B-frags
        unsigned int wv[8];
        #pragma unroll
        for (int ii = 0; ii < 8; ii++) {
            unsigned int t;
            asm("v_cvt_pk_bf16_f32 %0, %1, %2" : "=v"(t) : "v"(p[2 * ii]), "v"(p[2 * ii + 1]));
            wv[ii] = t;
        }
        unsigned int x0 = __shfl_xor(hi ? wv[0] : wv[2], 32);
        unsigned int x1 = __shfl_xor(hi ? wv[1] : wv[3], 32);
        unsigned int x2 = __shfl_xor(hi ? wv[4] : wv[6], 32);
        unsigned int x3 = __shfl_xor(hi ? wv[5] : wv[7], 32);
        int32x4 pf0i, pf1i;
        if (hi) {
            pf0i = (int32x4){(int)x0, (int)x1, (int)wv[2], (int)wv[3]};
            pf1i = (int32x4){(int)x2, (int)x3, (int)wv[6], (int)wv[7]};
        } else {
            pf0i = (int32x4){(int)wv[0], (int)wv[1], (int)x0, (int)x1};
            pf1i = (int32x4){(int)wv[4], (int)wv[5], (int)x2, (int)x3};
        }
        short8 pf0 = __builtin_bit_cast(short8, pf0i);
        short8 pf1 = __builtin_bit_cast(short8, pf1i);

        // PV (swapped): O^T[d][q] += Vt-frag x P-frag
        O0 = __builtin_amdgcn_mfma_f32_32x32x16_bf16(vf0, pf0, O0, 0, 0, 0);
        O0 = __builtin_amdgcn_mfma_f32_32x32x16_bf16(vf1, pf1, O0, 0, 0, 0);
        O1 = __builtin_amdgcn_mfma_f32_32x32x16_bf16(vf2, pf0, O1, 0, 0, 0);
        O1 = __builtin_amdgcn_mfma_f32_32x32x16_bf16(vf3, pf1, O1, 0, 0, 0);
    };

    __syncthreads();  // bias2 ready

    short8 kA[4], kB[4];
    loadk(kA, 0);
    for (int kt = 0; kt < 32; kt += 2) {
        loadk(kB, kt + 1);
        compute(kA, kt);
        if (kt < 30) loadk(kA, kt + 2);
        compute(kB, kt + 1);
    }

    // epilogue: normalize, LDS-bounce O^T -> row-major, coalesced stores
    float inv = 1.f / l_run;
    bf16_t* olw = &Ol[w * 32 * 68];
    #pragma unroll
    for (int r = 0; r < 16; r++) {
        int dr = (r & 3) + 8 * (r >> 2) + 4 * hi;
        olw[l31 * 68 + dr]      = f2b_rne(O0[r] * inv);
        olw[l31 * 68 + dr + 32] = f2b_rne(O1[r] * inv);
    }
    bf16_t* outp = attn_out + (size_t)(b * 1024 + q0 + w * 32) * 1024 + h * 64;
    #pragma unroll 4
    for (int i2 = 0; i2 < 32; i2++)
        outp[(size_t)i2 * 1024 + lane] = olw[i2 * 68 + lane];
}

// ---------------------------------------------------------------------------
extern "C" void kernel_launch(void* const* d_in, const int* in_sizes, int n_in,
                              void* d_out, int out_size, void* d_ws, size_t ws_size,
                              hipStream_t stream) {
    const float* hs   = (const float*)d_in[0];  // [8,1024,1024]
    const float* wqkv = (const float*)d_in[1];  // [3072,1024]
    const float* emb  = (const float*)d_in[2];  // [32,16]
    const float* wout = (const float*)d_in[3];  // [1024,1024]
    float* out = (float*)d_out;                 // [8,1024,1024] fp32

    char* p = (char*)d_ws;
    bf16_t* qkvb  = (bf16_t*)p; p += (size_t)8192 * 3072 * 2;  // 48 MB
    bf16_t* attnb = (bf16_t*)p; p += (size_t)8192 * 1024 * 2;  // 16 MB
    bf16_t* hsb   = (bf16_t*)p; p += (size_t)8192 * 1024 * 2;  // 16 MB
    bf16_t* wqkvb = (bf16_t*)p; p += (size_t)3072 * 1024 * 2;  //  6 MB
    bf16_t* woutb = (bf16_t*)p; p += (size_t)1024 * 1024 * 2;  //  2 MB
    bf16_t* klin  = (bf16_t*)p; p += (size_t)128 * 65536 * 2;  // 16 MB
    bf16_t* vt2   = (bf16_t*)p; p += (size_t)128 * 65536 * 2;  // 16 MB
    float*  tab   = (float*)p;                                 // 128 KB

    f2b_kernel<<<2048, 256, 0, stream>>>(hs, hsb, 8192 * 1024 / 4);
    f2b_kernel<<<768, 256, 0, stream>>>(wqkv, wqkvb, 3072 * 1024 / 4);
    f2b_kernel<<<256, 256, 0, stream>>>(wout, woutb, 1024 * 1024 / 4);
    build_bias_tab<<<8, 256, 0, stream>>>(emb, tab);

    gemm_mfma<bf16_t><<<1536, 256, 0, stream>>>(hsb, wqkvb, qkvb, 3072, 24);
    relayout_k<<<4096, 256, 0, stream>>>(qkvb, klin);
    relayout_v<<<4096, 256, 0, stream>>>(qkvb, vt2);
    attn_mfma4<<<1024, 256, 0, stream>>>(qkvb, tab, klin, vt2, attnb);
    gemm_mfma<float><<<512, 256, 0, stream>>>(attnb, woutb, out, 1024, 8);
}